// Round 13
// baseline (704.002 us; speedup 1.0000x reference)
//
#include <hip/hip_runtime.h>

typedef __attribute__((ext_vector_type(8))) short short8;
typedef __attribute__((ext_vector_type(8))) unsigned short ushort8;
typedef __attribute__((ext_vector_type(4))) float floatx4;

#define NBQ  1024     // max buckets (N <= 131072 @ 128 nodes/bucket)
#define NBLK 128      // sort blocks

__device__ __forceinline__ float bf2f(unsigned short u) {
    union { unsigned u; float f; } v; v.u = ((unsigned)u) << 16; return v.f;
}
__device__ __forceinline__ float bflo(unsigned u) {
    union { unsigned u; float f; } v; v.u = u << 16; return v.f;
}
__device__ __forceinline__ float bfhi(unsigned u) {
    union { unsigned u; float f; } v; v.u = u & 0xFFFF0000u; return v.f;
}
__device__ __forceinline__ unsigned short f2bf(float f) {
    union { float f; unsigned u; } v; v.f = f;
    unsigned r = v.u + 0x7FFFu + ((v.u >> 16) & 1u);
    return (unsigned short)(r >> 16);
}
__device__ __forceinline__ unsigned pack2bf(float a, float b) {
    return (unsigned)f2bf(a) | ((unsigned)f2bf(b) << 16);
}
__device__ __forceinline__ float lrelu(float x, float s) { return x >= 0.f ? x : s * x; }

// fp32 -> bf16 pairs, pre-scaled by dinv[node] (D^-1/2 absorbed into features)
__global__ __launch_bounds__(256) void cast_scale(const float* __restrict__ in, const float* __restrict__ dinv,
                                                  unsigned* __restrict__ outp, int npairs) {
    int i = blockIdx.x * 256 + threadIdx.x;
    if (i < npairs) {
        float s = dinv[i >> 6];
        float2 v = *(const float2*)(in + 2 * (size_t)i);
        outp[i] = pack2bf(v.x * s, v.y * s);
    }
}

// one-shot fp32 -> bf16 cast of 5 weight matrices into one packed buffer
// c0..c4 are cumulative PAIR counts of the segments
__global__ __launch_bounds__(256) void wcast(const float* __restrict__ w0, const float* __restrict__ w1,
                                             const float* __restrict__ w2, const float* __restrict__ w3,
                                             const float* __restrict__ w4, unsigned* __restrict__ outp,
                                             int c0, int c1, int c2, int c3, int c4) {
    int i = blockIdx.x * 256 + threadIdx.x;
    if (i >= c4) return;
    const float* src; int base;
    if      (i < c0) { src = w0; base = 0;  }
    else if (i < c1) { src = w1; base = c0; }
    else if (i < c2) { src = w2; base = c1; }
    else if (i < c3) { src = w3; base = c2; }
    else             { src = w4; base = c3; }
    float2 v = *(const float2*)(src + 2 * (size_t)(i - base));
    outp[i] = pack2bf(v.x, v.y);
}

// ---- CSR build: two-phase counting sort (bucket = 128 dst nodes), no global atomics ----
__global__ __launch_bounds__(256) void hist_k(const int* __restrict__ dst, int* __restrict__ cnt,
                                              int e, int et, int nb) {
    __shared__ int h[NBQ];
    for (int i = threadIdx.x; i < nb; i += 256) h[i] = 0;
    __syncthreads();
    int chunk = (et + NBLK - 1) / NBLK;
    int c0 = blockIdx.x * chunk;
    int c1 = c0 + chunk < et ? c0 + chunk : et;
    for (int i = c0 + (int)threadIdx.x; i < c1; i += 256) {
        int d = (i < e) ? dst[i] : (i - e);
        atomicAdd(&h[d >> 7], 1);
    }
    __syncthreads();
    for (int i = threadIdx.x; i < nb; i += 256) cnt[blockIdx.x * NBQ + i] = h[i];
}

__global__ __launch_bounds__(256) void btot_k(const int* __restrict__ cnt, int* __restrict__ btot, int nb) {
    int b = blockIdx.x * 256 + threadIdx.x;
    if (b >= nb) return;
    int s = 0;
    for (int blk = 0; blk < NBLK; ++blk) s += cnt[blk * NBQ + b];
    btot[b] = s;
}

__global__ __launch_bounds__(256) void bscan_k(const int* __restrict__ btot, int* __restrict__ bbase,
                                               int nb, int et) {
    __shared__ int sd[256];
    int t = threadIdx.x;
    int i0 = t * 4;
    int loc[4]; int s = 0;
    for (int j = 0; j < 4; ++j) { int i = i0 + j; loc[j] = (i < nb) ? btot[i] : 0; s += loc[j]; }
    sd[t] = s; __syncthreads();
    for (int off = 1; off < 256; off <<= 1) {
        int v = (t >= off) ? sd[t - off] : 0;
        __syncthreads();
        sd[t] += v;
        __syncthreads();
    }
    int run = sd[t] - s;
    for (int j = 0; j < 4; ++j) {
        int i = i0 + j;
        if (i < nb) { bbase[i] = run; run += loc[j]; }
    }
    if (t == 255) bbase[nb] = et;
}

__global__ __launch_bounds__(256) void scan_cnt(int* __restrict__ cnt, const int* __restrict__ bbase,
                                                int nb) {
    int b = blockIdx.x * 256 + threadIdx.x;
    if (b >= nb) return;
    int base = bbase[b];
    for (int blk = 0; blk < NBLK; ++blk) {
        int* p = &cnt[blk * NBQ + b];
        int t = *p; *p = base; base += t;
    }
}

__global__ __launch_bounds__(256) void scatter_k(const int* __restrict__ src, const int* __restrict__ dst,
                                                 const int* __restrict__ cnt,
                                                 int2* __restrict__ ebuf, int e, int et, int nb) {
    __shared__ int cur[NBQ];
    for (int i = threadIdx.x; i < nb; i += 256) cur[i] = cnt[blockIdx.x * NBQ + i];
    __syncthreads();
    int chunk = (et + NBLK - 1) / NBLK;
    int c0 = blockIdx.x * chunk;
    int c1 = c0 + chunk < et ? c0 + chunk : et;
    for (int i = c0 + (int)threadIdx.x; i < c1; i += 256) {
        int s, d;
        if (i < e) { s = src[i]; d = dst[i]; }
        else       { s = d = i - e; }            // self loop
        int pos = atomicAdd(&cur[d >> 7], 1);
        int2 ent; ent.x = s; ent.y = d;
        ebuf[pos] = ent;
    }
}

// fused: per-bucket degree count + scan -> offsets/dinv, then node-granular CSR
// placement with LDS cursors (ebuf segment stays L2-hot between the two passes)
__global__ __launch_bounds__(256) void finalize_k(const int2* __restrict__ ebuf, const int* __restrict__ bbase,
                                                  int* __restrict__ offsets, float* __restrict__ dinv,
                                                  int* __restrict__ csr_s, int n, int et) {
    __shared__ int ldeg[128];
    __shared__ int lscan[128];
    __shared__ int cur[128];
    int b = blockIdx.x;
    int n0 = b << 7;
    if (threadIdx.x < 128) ldeg[threadIdx.x] = 0;
    __syncthreads();
    int e0 = bbase[b], e1 = bbase[b + 1];
    for (int i = e0 + (int)threadIdx.x; i < e1; i += 256)
        atomicAdd(&ldeg[ebuf[i].y & 127], 1);
    __syncthreads();
    if (threadIdx.x < 128) lscan[threadIdx.x] = ldeg[threadIdx.x];
    __syncthreads();
    for (int off = 1; off < 128; off <<= 1) {
        int v = 0;
        if (threadIdx.x < 128 && (int)threadIdx.x >= off) v = lscan[threadIdx.x - off];
        __syncthreads();
        if (threadIdx.x < 128) lscan[threadIdx.x] += v;
        __syncthreads();
    }
    if (threadIdx.x < 128) {
        int base = e0 + lscan[threadIdx.x] - ldeg[threadIdx.x];   // exclusive
        cur[threadIdx.x] = base;
        int node = n0 + threadIdx.x;
        if (node < n) {
            offsets[node] = base;
            dinv[node] = rsqrtf((float)ldeg[threadIdx.x]);         // deg >= 1 (self loop)
        }
    }
    if (b == 0 && threadIdx.x == 0) offsets[n] = et;
    __syncthreads();
    for (int i = e0 + (int)threadIdx.x; i < e1; i += 256) {
        int2 ent = ebuf[i];
        int pos = atomicAdd(&cur[ent.y & 127], 1);
        csr_s[pos] = ent.x;
    }
}

// ---------------- propagation: out[d] = scale(d) * sum_{s in N(d)} x[s], 128 bf16 feats ----------------
// Unweighted neighbor sum (P = D^-1/2 A D^-1/2 decomposed); 4 slots x 16 lanes, uint4/lane.
// sq: scale = dinv^2 (first hop, absorbs D^-1); else scale = dinv (second hop, D^-1/2).

__global__ __launch_bounds__(256) void prop_kernel(const uint4* __restrict__ xin, const int* __restrict__ offs,
                                                   const int* __restrict__ csr_s, const float* __restrict__ dinv,
                                                   int sq, uint4* __restrict__ out, int n) {
    int node = blockIdx.x * 4 + (threadIdx.x >> 6);
    if (node >= n) return;
    int lane = threadIdx.x & 63;
    int slot = lane >> 4;      // 0..3
    int li   = lane & 15;      // uint4 index within 16-uint4 row
    int beg = offs[node], end = offs[node + 1];
    float a0=0.f,a1=0.f,a2=0.f,a3=0.f,a4=0.f,a5=0.f,a6=0.f,a7=0.f;
    for (int base = beg; base < end; base += 64) {
        int cnt = end - base; if (cnt > 64) cnt = 64;
        int sj = (lane < cnt) ? csr_s[base + lane] : 0;
        for (int t = 0; t < cnt; t += 4) {
            int idx  = t + slot;
            int s = __shfl(sj, idx < cnt ? idx : 0, 64);
            if (idx < cnt) {
                uint4 u = xin[(size_t)s * 16 + li];
                a0 += bflo(u.x); a1 += bfhi(u.x);
                a2 += bflo(u.y); a3 += bfhi(u.y);
                a4 += bflo(u.z); a5 += bfhi(u.z);
                a6 += bflo(u.w); a7 += bfhi(u.w);
            }
        }
    }
    // combine the 4 slot partials (lanes differing in bits 4,5 hold same features)
    a0 += __shfl_xor(a0, 16, 64); a0 += __shfl_xor(a0, 32, 64);
    a1 += __shfl_xor(a1, 16, 64); a1 += __shfl_xor(a1, 32, 64);
    a2 += __shfl_xor(a2, 16, 64); a2 += __shfl_xor(a2, 32, 64);
    a3 += __shfl_xor(a3, 16, 64); a3 += __shfl_xor(a3, 32, 64);
    a4 += __shfl_xor(a4, 16, 64); a4 += __shfl_xor(a4, 32, 64);
    a5 += __shfl_xor(a5, 16, 64); a5 += __shfl_xor(a5, 32, 64);
    a6 += __shfl_xor(a6, 16, 64); a6 += __shfl_xor(a6, 32, 64);
    a7 += __shfl_xor(a7, 16, 64); a7 += __shfl_xor(a7, 32, 64);
    if (slot == 0) {
        float f = dinv[node];
        if (sq) f *= f;
        uint4 o;
        o.x = pack2bf(a0 * f, a1 * f); o.y = pack2bf(a2 * f, a3 * f);
        o.z = pack2bf(a4 * f, a5 * f); o.w = pack2bf(a6 * f, a7 * f);
        out[(size_t)node * 16 + li] = o;
    }
}

// ---------------- MFMA GEMM: C[M,Nc] = act(A[M,K] @ B[K,Nc] + bias) [* oscale] ----------------
// Proven 64x64 MFMA micro-shape; NT 64-col B-tiles per block (A staged/read ONCE for NT*64 cols).
// A bf16 [M,K], B bf16 (pre-cast weights), bias fp32, C bf16. K%32==0, Nc == gridDim.y*NT*64.

template <int NT>
__global__ __launch_bounds__(256) void gemm_mfma(const unsigned short* __restrict__ A,
                                                 const unsigned short* __restrict__ Bw,
                                                 const float* __restrict__ bias, unsigned short* __restrict__ C,
                                                 const float* __restrict__ oscale,
                                                 int M, int K, int Nc, float slope, int act) {
    __shared__ __align__(16) unsigned short As[64 * 40];
    __shared__ __align__(16) unsigned short Bs[64 * NT * 40];
    const int tid  = threadIdx.x;
    const int wave = tid >> 6;
    const int lane = tid & 63;
    const int q    = lane >> 4;
    const int r16  = lane & 15;
    const int m0 = blockIdx.x * 64;
    const int n0 = blockIdx.y * (64 * NT);

    floatx4 acc[NT][4];
#pragma unroll
    for (int nt = 0; nt < NT; ++nt)
#pragma unroll
        for (int j = 0; j < 4; ++j) acc[nt][j] = (floatx4){0.f,0.f,0.f,0.f};

    const int am = tid >> 2;         // 0..63 (tile row)
    const int ak = (tid & 3) * 8;    // 0..24
    const int bk = tid >> 3;         // 0..31 (k within step)
    const int bn = (tid & 7) * 8;    // 0..56

    for (int k0 = 0; k0 < K; k0 += 32) {
        // stage A tile [64][32] bf16 (straight 16B copy), row stride 40
        {
            int gm = m0 + am;
            ushort8 sv;
            if (gm < M) {
                sv = *(const ushort8*)(A + (size_t)gm * K + k0 + ak);
            } else {
                for (int j = 0; j < 8; ++j) sv[j] = 0;
            }
            *(ushort8*)(&As[am * 40 + ak]) = sv;
        }
        // stage B tiles [32][NT*64] transposed -> Bs[n][k] (bf16 source, no convert)
#pragma unroll
        for (int nt = 0; nt < NT; ++nt) {
            ushort8 bv = *(const ushort8*)(Bw + (size_t)(k0 + bk) * Nc + n0 + nt * 64 + bn);
            for (int j = 0; j < 8; ++j) Bs[(nt * 64 + bn + j) * 40 + bk] = bv[j];
        }
        __syncthreads();
        short8 a0 = *(const short8*)(&As[(r16) * 40 + q * 8]);
        short8 a1 = *(const short8*)(&As[(16 + r16) * 40 + q * 8]);
        short8 a2 = *(const short8*)(&As[(32 + r16) * 40 + q * 8]);
        short8 a3 = *(const short8*)(&As[(48 + r16) * 40 + q * 8]);
#pragma unroll
        for (int nt = 0; nt < NT; ++nt) {
            short8 bfrag = *(const short8*)(&Bs[(nt * 64 + wave * 16 + r16) * 40 + q * 8]);
            acc[nt][0] = __builtin_amdgcn_mfma_f32_16x16x32_bf16(a0, bfrag, acc[nt][0], 0, 0, 0);
            acc[nt][1] = __builtin_amdgcn_mfma_f32_16x16x32_bf16(a1, bfrag, acc[nt][1], 0, 0, 0);
            acc[nt][2] = __builtin_amdgcn_mfma_f32_16x16x32_bf16(a2, bfrag, acc[nt][2], 0, 0, 0);
            acc[nt][3] = __builtin_amdgcn_mfma_f32_16x16x32_bf16(a3, bfrag, acc[nt][3], 0, 0, 0);
        }
        __syncthreads();
    }
    // epilogue: C/D layout col=lane&15, row=(lane>>4)*4+reg
#pragma unroll
    for (int nt = 0; nt < NT; ++nt) {
        int cn = n0 + nt * 64 + wave * 16 + r16;
        float bv = bias ? bias[cn] : 0.f;
        for (int ms = 0; ms < 4; ++ms)
            for (int rr = 0; rr < 4; ++rr) {
                int cm = m0 + ms * 16 + q * 4 + rr;
                if (cm < M) {
                    float v = acc[nt][ms][rr] + bv;
                    if (act) v = lrelu(v, slope);
                    if (oscale) v *= oscale[cm];
                    C[(size_t)cm * Nc + cn] = f2bf(v);
                }
            }
    }
}

// ---------------- GAT ----------------

__global__ __launch_bounds__(256) void gat_dots(const unsigned short* __restrict__ hg, const float* __restrict__ att_s,
                                                const float* __restrict__ att_d,
                                                float* __restrict__ a_s, float* __restrict__ a_d, int n) {
    int node = blockIdx.x * 4 + (threadIdx.x >> 6);
    if (node >= n) return;
    int lane = threadIdx.x & 63;
    float v  = bf2f(hg[(size_t)node * 64 + lane]);
    float s1 = v * att_s[lane];
    float s2 = v * att_d[lane];
    for (int off = 32; off > 0; off >>= 1) {
        s1 += __shfl_xor(s1, off, 64);
        s2 += __shfl_xor(s2, off, 64);
    }
    if (lane == 0) { a_s[node] = s1; a_d[node] = s2; }
}

// 8 edges in flight: 8 slots x 8 lanes, uint4 (8 feats) per lane (row = 64 bf16 = 8 uint4).
// No segment-max pass: e = lrelu(a_s+a_d) is O(1..10) << 88, exp(e) fp32-safe; shift cancels.
__global__ __launch_bounds__(256) void gat_agg(const uint4* __restrict__ hg, const float* __restrict__ a_s,
                                               const float* __restrict__ a_d, const int* __restrict__ offs,
                                               const int* __restrict__ csr_s, const float* __restrict__ bg,
                                               uint4* __restrict__ out, int n) {
    int node = blockIdx.x * 4 + (threadIdx.x >> 6);
    if (node >= n) return;
    int lane = threadIdx.x & 63;
    int slot = lane >> 3;      // 0..7
    int li   = lane & 7;       // uint4 index within row
    int beg = offs[node], end = offs[node + 1];
    float ad = a_d[node];
    float a0=0.f,a1=0.f,a2=0.f,a3=0.f,a4=0.f,a5=0.f,a6=0.f,a7=0.f, ssum=0.f;
    for (int base = beg; base < end; base += 64) {
        int cnt = end - base; if (cnt > 64) cnt = 64;
        int sj = 0; float wj = 0.f;
        if (lane < cnt) {
            sj = csr_s[base + lane];
            float e = a_s[sj] + ad;
            e = e < 0.f ? 0.2f * e : e;
            wj = __expf(e);
        }
        for (int t = 0; t < cnt; t += 8) {
            int idx  = t + slot;
            int idxc = idx < cnt ? idx : 0;
            int   s = __shfl(sj, idxc, 64);
            float w = __shfl(wj, idxc, 64);
            if (idx >= cnt) w = 0.f;
            ssum += w;
            uint4 u = hg[(size_t)s * 8 + li];
            a0 = fmaf(w, bflo(u.x), a0); a1 = fmaf(w, bfhi(u.x), a1);
            a2 = fmaf(w, bflo(u.y), a2); a3 = fmaf(w, bfhi(u.y), a3);
            a4 = fmaf(w, bflo(u.z), a4); a5 = fmaf(w, bfhi(u.z), a5);
            a6 = fmaf(w, bflo(u.w), a6); a7 = fmaf(w, bfhi(u.w), a7);
        }
    }
    for (int off = 8; off <= 32; off <<= 1) {
        a0 += __shfl_xor(a0, off, 64); a1 += __shfl_xor(a1, off, 64);
        a2 += __shfl_xor(a2, off, 64); a3 += __shfl_xor(a3, off, 64);
        a4 += __shfl_xor(a4, off, 64); a5 += __shfl_xor(a5, off, 64);
        a6 += __shfl_xor(a6, off, 64); a7 += __shfl_xor(a7, off, 64);
        ssum += __shfl_xor(ssum, off, 64);
    }
    if (slot == 0) {
        float inv = 1.0f / ssum;
        int f0 = li * 8;
        uint4 o;
        o.x = pack2bf(lrelu(a0 * inv + bg[f0 + 0], 0.1f), lrelu(a1 * inv + bg[f0 + 1], 0.1f));
        o.y = pack2bf(lrelu(a2 * inv + bg[f0 + 2], 0.1f), lrelu(a3 * inv + bg[f0 + 3], 0.1f));
        o.z = pack2bf(lrelu(a4 * inv + bg[f0 + 4], 0.1f), lrelu(a5 * inv + bg[f0 + 5], 0.1f));
        o.w = pack2bf(lrelu(a6 * inv + bg[f0 + 6], 0.1f), lrelu(a7 * inv + bg[f0 + 7], 0.1f));
        out[(size_t)node * 8 + li] = o;
    }
}

// ---------------- final small GEMM [Ng,256]@[256,8] + bias -> fp32 ----------------

__global__ __launch_bounds__(256) void final_gemm(const unsigned short* __restrict__ m2, const float* __restrict__ W3,
                                                  const float* __restrict__ b3,
                                                  float* __restrict__ out, int ng) {
    int idx = blockIdx.x * 256 + threadIdx.x;
    if (idx >= ng * 8) return;
    int r = idx >> 3, c = idx & 7;
    float acc = b3[c];
    const unsigned short* row = m2 + (size_t)r * 256;
    for (int k = 0; k < 256; ++k) acc = fmaf(bf2f(row[k]), W3[k * 8 + c], acc);
    out[idx] = acc;
}

// ---------------- launch ----------------

extern "C" void kernel_launch(void* const* d_in, const int* in_sizes, int n_in,
                              void* d_out, int out_size, void* d_ws, size_t ws_size,
                              hipStream_t stream) {
    const int N  = in_sizes[0] / 128;
    const int E  = in_sizes[1] / 2;
    const int ET = E + N;
    const int Ng = N / 10;
    const int NB = (N + 127) / 128;   // dst buckets (<= NBQ)

    const float* x    = (const float*)d_in[0];
    const int*   src  = (const int*)d_in[1];
    const int*   dst  = src + E;
    const float* W1   = (const float*)d_in[2];
    const float* b1   = (const float*)d_in[3];
    const float* W2   = (const float*)d_in[4];
    const float* b2   = (const float*)d_in[5];
    const float* Wg   = (const float*)d_in[6];
    const float* atts = (const float*)d_in[7];
    const float* attd = (const float*)d_in[8];
    const float* bg   = (const float*)d_in[9];
    const float* Wl1  = (const float*)d_in[10];
    const float* bl1  = (const float*)d_in[11];
    const float* Wl2  = (const float*)d_in[12];
    const float* bl2  = (const float*)d_in[13];
    const float* Wl3  = (const float*)d_in[14];
    const float* bl3  = (const float*)d_in[15];
    float* out = (float*)d_out;

    // bf16 weight buffer segment sizes (pairs)
    const int p1 = in_sizes[2] / 2;    // W1
    const int p2 = in_sizes[4] / 2;    // W2
    const int p3 = in_sizes[6] / 2;    // Wg
    const int p4 = in_sizes[10] / 2;   // Wl1
    const int p5 = in_sizes[12] / 2;   // Wl2
    const int c0 = p1, c1 = c0 + p2, c2 = c1 + p3, c3 = c2 + p4, c4 = c3 + p5;

    // workspace carve (all feature buffers bf16, 16B-aligned rows)
    char* p = (char*)d_ws;
    auto alloc = [&](size_t bytes) { char* r = p; p += (bytes + 255) & ~(size_t)255; return r; };
    unsigned short* xb = (unsigned short*)alloc((size_t)N * 128 * 2);
    unsigned short* A  = (unsigned short*)alloc((size_t)N * 128 * 2);
    unsigned short* Bb = (unsigned short*)alloc((size_t)N * 128 * 2);
    int*   csr_s   = (int*)  alloc((size_t)ET * 4);
    int*   cnt     = (int*)  alloc((size_t)NBLK * NBQ * 4);
    int*   btot    = (int*)  alloc((size_t)(NBQ + 1) * 4);
    int*   bbase   = (int*)  alloc((size_t)(NBQ + 1) * 4);
    float* dinv    = (float*)alloc((size_t)N * 4);
    int*   offsets = (int*)  alloc((size_t)(N + 1) * 4);
    float* a_s     = (float*)alloc((size_t)N * 4);
    float* a_d     = (float*)alloc((size_t)N * 4);
    unsigned short* wb = (unsigned short*)alloc((size_t)c4 * 4);  // packed bf16 weights
    // ebuf ({src,dst} pairs, ET*8 bytes) aliases Bb (N*128*2 = 25.6MB > 13.6MB);
    // its lifetime ends before Bb's first write.
    int2*  ebuf    = (int2*)Bb;

    const unsigned short* W1b  = wb;
    const unsigned short* W2b  = wb + 2 * (size_t)c0;
    const unsigned short* Wgb  = wb + 2 * (size_t)c1;
    const unsigned short* Wl1b = wb + 2 * (size_t)c2;
    const unsigned short* Wl2b = wb + 2 * (size_t)c3;

    const int pg = (N + 3) / 4;

    hist_k    <<<NBLK, 256, 0, stream>>>(dst, cnt, E, ET, NB);
    btot_k    <<<(NB + 255) / 256, 256, 0, stream>>>(cnt, btot, NB);
    bscan_k   <<<1, 256, 0, stream>>>(btot, bbase, NB, ET);
    scan_cnt  <<<(NB + 255) / 256, 256, 0, stream>>>(cnt, bbase, NB);
    scatter_k <<<NBLK, 256, 0, stream>>>(src, dst, cnt, ebuf, E, ET, NB);
    finalize_k<<<NB, 256, 0, stream>>>(ebuf, bbase, offsets, dinv, csr_s, N, ET);
    wcast     <<<(c4 + 255) / 256, 256, 0, stream>>>(W1, W2, Wg, Wl1, Wl2, (unsigned*)wb, c0, c1, c2, c3, c4);
    cast_scale<<<(N * 64 + 255) / 256, 256, 0, stream>>>(x, dinv, (unsigned*)xb, N * 64);

    // conv1: u = D^-1/2 x (cast) ; A = D^-1 A u ; Bb = D^-1/2 A A' = P^2 x ; h1' = lrelu(...)*dinv
    prop_kernel<<<pg, 256, 0, stream>>>((const uint4*)xb, offsets, csr_s, dinv, 1, (uint4*)A,  N);
    prop_kernel<<<pg, 256, 0, stream>>>((const uint4*)A,  offsets, csr_s, dinv, 0, (uint4*)Bb, N);
    dim3 g1((N + 63) / 64, 1);
    gemm_mfma<2><<<g1, 256, 0, stream>>>(Bb, W1b, b1, A, dinv, N, 128, 128, 0.1f, 1);
    // conv2 (input already dinv-prescaled by gemm1 epilogue)
    prop_kernel<<<pg, 256, 0, stream>>>((const uint4*)A,  offsets, csr_s, dinv, 1, (uint4*)Bb, N);
    prop_kernel<<<pg, 256, 0, stream>>>((const uint4*)Bb, offsets, csr_s, dinv, 0, (uint4*)A,  N);
    gemm_mfma<2><<<g1, 256, 0, stream>>>(A, W2b, b2, Bb, nullptr, N, 128, 128, 0.1f, 1);
    // GAT: hg = h2 @ Wg (no bias/act), then attention aggregate
    gemm_mfma<1><<<g1, 256, 0, stream>>>(Bb, Wgb, nullptr, A, nullptr, N, 128, 64, 0.f, 0);
    gat_dots<<<pg, 256, 0, stream>>>(A, atts, attd, a_s, a_d, N);
    gat_agg <<<pg, 256, 0, stream>>>((const uint4*)A, a_s, a_d, offsets, csr_s, bg, (uint4*)Bb, N);
    // MLP: Bb viewed as [Ng, 640] bf16
    dim3 g3((Ng + 63) / 64, 2);
    gemm_mfma<4><<<g3, 256, 0, stream>>>(Bb, Wl1b, bl1, A, nullptr, Ng, 640, 512, 0.1f, 1);
    dim3 g4((Ng + 63) / 64, 1);
    gemm_mfma<4><<<g4, 256, 0, stream>>>(A, Wl2b, bl2, Bb, nullptr, Ng, 512, 256, 0.1f, 1);
    final_gemm<<<(Ng * 8 + 255) / 256, 256, 0, stream>>>(Bb, Wl3, bl3, out, Ng);
}

// Round 14
// 652.030 us; speedup vs baseline: 1.0797x; 1.0797x over previous
//
#include <hip/hip_runtime.h>

typedef __attribute__((ext_vector_type(8))) short short8;
typedef __attribute__((ext_vector_type(8))) unsigned short ushort8;
typedef __attribute__((ext_vector_type(4))) float floatx4;

#define NBQ  1024     // max buckets (N <= 131072 @ 128 nodes/bucket)
#define NBLK 128      // sort blocks

__device__ __forceinline__ float bf2f(unsigned short u) {
    union { unsigned u; float f; } v; v.u = ((unsigned)u) << 16; return v.f;
}
__device__ __forceinline__ float bflo(unsigned u) {
    union { unsigned u; float f; } v; v.u = u << 16; return v.f;
}
__device__ __forceinline__ float bfhi(unsigned u) {
    union { unsigned u; float f; } v; v.u = u & 0xFFFF0000u; return v.f;
}
__device__ __forceinline__ unsigned short f2bf(float f) {
    union { float f; unsigned u; } v; v.f = f;
    unsigned r = v.u + 0x7FFFu + ((v.u >> 16) & 1u);
    return (unsigned short)(r >> 16);
}
__device__ __forceinline__ unsigned pack2bf(float a, float b) {
    return (unsigned)f2bf(a) | ((unsigned)f2bf(b) << 16);
}
__device__ __forceinline__ float lrelu(float x, float s) { return x >= 0.f ? x : s * x; }

// fp32 -> bf16 pairs, pre-scaled by dinv[node] (D^-1/2 absorbed into features)
__global__ __launch_bounds__(256) void cast_scale(const float* __restrict__ in, const float* __restrict__ dinv,
                                                  unsigned* __restrict__ outp, int npairs) {
    int i = blockIdx.x * 256 + threadIdx.x;
    if (i < npairs) {
        float s = dinv[i >> 6];
        float2 v = *(const float2*)(in + 2 * (size_t)i);
        outp[i] = pack2bf(v.x * s, v.y * s);
    }
}

// one-shot fp32 -> bf16 cast of 5 weight matrices into one packed buffer
// c0..c4 are cumulative PAIR counts of the segments
__global__ __launch_bounds__(256) void wcast(const float* __restrict__ w0, const float* __restrict__ w1,
                                             const float* __restrict__ w2, const float* __restrict__ w3,
                                             const float* __restrict__ w4, unsigned* __restrict__ outp,
                                             int c0, int c1, int c2, int c3, int c4) {
    int i = blockIdx.x * 256 + threadIdx.x;
    if (i >= c4) return;
    const float* src; int base;
    if      (i < c0) { src = w0; base = 0;  }
    else if (i < c1) { src = w1; base = c0; }
    else if (i < c2) { src = w2; base = c1; }
    else if (i < c3) { src = w3; base = c2; }
    else             { src = w4; base = c3; }
    float2 v = *(const float2*)(src + 2 * (size_t)(i - base));
    outp[i] = pack2bf(v.x, v.y);
}

// ---- CSR build: two-phase counting sort (bucket = 128 dst nodes), no global atomics ----
__global__ __launch_bounds__(256) void hist_k(const int* __restrict__ dst, int* __restrict__ cnt,
                                              int e, int et, int nb) {
    __shared__ int h[NBQ];
    for (int i = threadIdx.x; i < nb; i += 256) h[i] = 0;
    __syncthreads();
    int chunk = (et + NBLK - 1) / NBLK;
    int c0 = blockIdx.x * chunk;
    int c1 = c0 + chunk < et ? c0 + chunk : et;
    for (int i = c0 + (int)threadIdx.x; i < c1; i += 256) {
        int d = (i < e) ? dst[i] : (i - e);
        atomicAdd(&h[d >> 7], 1);
    }
    __syncthreads();
    for (int i = threadIdx.x; i < nb; i += 256) cnt[blockIdx.x * NBQ + i] = h[i];
}

__global__ __launch_bounds__(256) void btot_k(const int* __restrict__ cnt, int* __restrict__ btot, int nb) {
    int b = blockIdx.x * 256 + threadIdx.x;
    if (b >= nb) return;
    int s = 0;
    for (int blk = 0; blk < NBLK; ++blk) s += cnt[blk * NBQ + b];
    btot[b] = s;
}

__global__ __launch_bounds__(256) void bscan_k(const int* __restrict__ btot, int* __restrict__ bbase,
                                               int nb, int et) {
    __shared__ int sd[256];
    int t = threadIdx.x;
    int i0 = t * 4;
    int loc[4]; int s = 0;
    for (int j = 0; j < 4; ++j) { int i = i0 + j; loc[j] = (i < nb) ? btot[i] : 0; s += loc[j]; }
    sd[t] = s; __syncthreads();
    for (int off = 1; off < 256; off <<= 1) {
        int v = (t >= off) ? sd[t - off] : 0;
        __syncthreads();
        sd[t] += v;
        __syncthreads();
    }
    int run = sd[t] - s;
    for (int j = 0; j < 4; ++j) {
        int i = i0 + j;
        if (i < nb) { bbase[i] = run; run += loc[j]; }
    }
    if (t == 255) bbase[nb] = et;
}

__global__ __launch_bounds__(256) void scan_cnt(int* __restrict__ cnt, const int* __restrict__ bbase,
                                                int nb) {
    int b = blockIdx.x * 256 + threadIdx.x;
    if (b >= nb) return;
    int base = bbase[b];
    for (int blk = 0; blk < NBLK; ++blk) {
        int* p = &cnt[blk * NBQ + b];
        int t = *p; *p = base; base += t;
    }
}

__global__ __launch_bounds__(256) void scatter_k(const int* __restrict__ src, const int* __restrict__ dst,
                                                 const int* __restrict__ cnt,
                                                 int2* __restrict__ ebuf, int e, int et, int nb) {
    __shared__ int cur[NBQ];
    for (int i = threadIdx.x; i < nb; i += 256) cur[i] = cnt[blockIdx.x * NBQ + i];
    __syncthreads();
    int chunk = (et + NBLK - 1) / NBLK;
    int c0 = blockIdx.x * chunk;
    int c1 = c0 + chunk < et ? c0 + chunk : et;
    for (int i = c0 + (int)threadIdx.x; i < c1; i += 256) {
        int s, d;
        if (i < e) { s = src[i]; d = dst[i]; }
        else       { s = d = i - e; }            // self loop
        int pos = atomicAdd(&cur[d >> 7], 1);
        int2 ent; ent.x = s; ent.y = d;
        ebuf[pos] = ent;
    }
}

// fused: per-bucket degree count + scan -> offsets/dinv, then node-granular CSR
// placement with LDS cursors (ebuf segment stays L2-hot between the two passes)
__global__ __launch_bounds__(256) void finalize_k(const int2* __restrict__ ebuf, const int* __restrict__ bbase,
                                                  int* __restrict__ offsets, float* __restrict__ dinv,
                                                  int* __restrict__ csr_s, int n, int et) {
    __shared__ int ldeg[128];
    __shared__ int lscan[128];
    __shared__ int cur[128];
    int b = blockIdx.x;
    int n0 = b << 7;
    if (threadIdx.x < 128) ldeg[threadIdx.x] = 0;
    __syncthreads();
    int e0 = bbase[b], e1 = bbase[b + 1];
    for (int i = e0 + (int)threadIdx.x; i < e1; i += 256)
        atomicAdd(&ldeg[ebuf[i].y & 127], 1);
    __syncthreads();
    if (threadIdx.x < 128) lscan[threadIdx.x] = ldeg[threadIdx.x];
    __syncthreads();
    for (int off = 1; off < 128; off <<= 1) {
        int v = 0;
        if (threadIdx.x < 128 && (int)threadIdx.x >= off) v = lscan[threadIdx.x - off];
        __syncthreads();
        if (threadIdx.x < 128) lscan[threadIdx.x] += v;
        __syncthreads();
    }
    if (threadIdx.x < 128) {
        int base = e0 + lscan[threadIdx.x] - ldeg[threadIdx.x];   // exclusive
        cur[threadIdx.x] = base;
        int node = n0 + threadIdx.x;
        if (node < n) {
            offsets[node] = base;
            dinv[node] = rsqrtf((float)ldeg[threadIdx.x]);         // deg >= 1 (self loop)
        }
    }
    if (b == 0 && threadIdx.x == 0) offsets[n] = et;
    __syncthreads();
    for (int i = e0 + (int)threadIdx.x; i < e1; i += 256) {
        int2 ent = ebuf[i];
        int pos = atomicAdd(&cur[ent.y & 127], 1);
        csr_s[pos] = ent.x;
    }
}

// ---------------- propagation: out[d] = scale(d) * sum_{s in N(d)} x[s], 128 bf16 feats ----------------
// Unweighted neighbor sum (P = D^-1/2 A D^-1/2 decomposed); 4 slots x 16 lanes, uint4/lane.
// sq: scale = dinv^2 (first hop, absorbs D^-1); else scale = dinv (second hop, D^-1/2).

__global__ __launch_bounds__(256) void prop_kernel(const uint4* __restrict__ xin, const int* __restrict__ offs,
                                                   const int* __restrict__ csr_s, const float* __restrict__ dinv,
                                                   int sq, uint4* __restrict__ out, int n) {
    int node = blockIdx.x * 4 + (threadIdx.x >> 6);
    if (node >= n) return;
    int lane = threadIdx.x & 63;
    int slot = lane >> 4;      // 0..3
    int li   = lane & 15;      // uint4 index within 16-uint4 row
    int beg = offs[node], end = offs[node + 1];
    float a0=0.f,a1=0.f,a2=0.f,a3=0.f,a4=0.f,a5=0.f,a6=0.f,a7=0.f;
    for (int base = beg; base < end; base += 64) {
        int cnt = end - base; if (cnt > 64) cnt = 64;
        int sj = (lane < cnt) ? csr_s[base + lane] : 0;
        for (int t = 0; t < cnt; t += 4) {
            int idx  = t + slot;
            int s = __shfl(sj, idx < cnt ? idx : 0, 64);
            if (idx < cnt) {
                uint4 u = xin[(size_t)s * 16 + li];
                a0 += bflo(u.x); a1 += bfhi(u.x);
                a2 += bflo(u.y); a3 += bfhi(u.y);
                a4 += bflo(u.z); a5 += bfhi(u.z);
                a6 += bflo(u.w); a7 += bfhi(u.w);
            }
        }
    }
    // combine the 4 slot partials (lanes differing in bits 4,5 hold same features)
    a0 += __shfl_xor(a0, 16, 64); a0 += __shfl_xor(a0, 32, 64);
    a1 += __shfl_xor(a1, 16, 64); a1 += __shfl_xor(a1, 32, 64);
    a2 += __shfl_xor(a2, 16, 64); a2 += __shfl_xor(a2, 32, 64);
    a3 += __shfl_xor(a3, 16, 64); a3 += __shfl_xor(a3, 32, 64);
    a4 += __shfl_xor(a4, 16, 64); a4 += __shfl_xor(a4, 32, 64);
    a5 += __shfl_xor(a5, 16, 64); a5 += __shfl_xor(a5, 32, 64);
    a6 += __shfl_xor(a6, 16, 64); a6 += __shfl_xor(a6, 32, 64);
    a7 += __shfl_xor(a7, 16, 64); a7 += __shfl_xor(a7, 32, 64);
    if (slot == 0) {
        float f = dinv[node];
        if (sq) f *= f;
        uint4 o;
        o.x = pack2bf(a0 * f, a1 * f); o.y = pack2bf(a2 * f, a3 * f);
        o.z = pack2bf(a4 * f, a5 * f); o.w = pack2bf(a6 * f, a7 * f);
        out[(size_t)node * 16 + li] = o;
    }
}

// ---------------- MFMA GEMM: C[M,Nc] = act(A[M,K] @ B[K,Nc] + bias) [* oscale] ----------------
// Proven round-12 64x64 tile, blockIdx.y = 64-col B tile. A bf16, B bf16 (pre-cast
// weights, straight-copy staging), bias fp32, C bf16. K%32==0, Nc%64==0.

__global__ __launch_bounds__(256) void gemm_mfma(const unsigned short* __restrict__ A,
                                                 const unsigned short* __restrict__ Bw,
                                                 const float* __restrict__ bias, unsigned short* __restrict__ C,
                                                 const float* __restrict__ oscale,
                                                 int M, int K, int Nc, float slope, int act) {
    __shared__ __align__(16) unsigned short As[64 * 40];
    __shared__ __align__(16) unsigned short Bs[64 * 40];
    const int tid  = threadIdx.x;
    const int wave = tid >> 6;
    const int lane = tid & 63;
    const int q    = lane >> 4;
    const int r16  = lane & 15;
    const int m0 = blockIdx.x * 64;
    const int n0 = blockIdx.y * 64;

    floatx4 acc0 = {0.f,0.f,0.f,0.f}, acc1 = acc0, acc2 = acc0, acc3 = acc0;

    const int am = tid >> 2;         // 0..63 (tile row)
    const int ak = (tid & 3) * 8;    // 0..24
    const int bk = tid >> 3;         // 0..31 (k within step)
    const int bn = (tid & 7) * 8;    // 0..56

    for (int k0 = 0; k0 < K; k0 += 32) {
        // stage A tile [64][32] bf16 (straight 16B copy), row stride 40
        {
            int gm = m0 + am;
            ushort8 sv;
            if (gm < M) {
                sv = *(const ushort8*)(A + (size_t)gm * K + k0 + ak);
            } else {
                for (int j = 0; j < 8; ++j) sv[j] = 0;
            }
            *(ushort8*)(&As[am * 40 + ak]) = sv;
        }
        // stage B tile [32][64] transposed -> Bs[n][k] (bf16 source, straight copy)
        {
            ushort8 bv = *(const ushort8*)(Bw + (size_t)(k0 + bk) * Nc + n0 + bn);
            for (int j = 0; j < 8; ++j) Bs[(bn + j) * 40 + bk] = bv[j];
        }
        __syncthreads();
        short8 bfrag = *(const short8*)(&Bs[(wave * 16 + r16) * 40 + q * 8]);
        short8 a0 = *(const short8*)(&As[(r16) * 40 + q * 8]);
        short8 a1 = *(const short8*)(&As[(16 + r16) * 40 + q * 8]);
        short8 a2 = *(const short8*)(&As[(32 + r16) * 40 + q * 8]);
        short8 a3 = *(const short8*)(&As[(48 + r16) * 40 + q * 8]);
        acc0 = __builtin_amdgcn_mfma_f32_16x16x32_bf16(a0, bfrag, acc0, 0, 0, 0);
        acc1 = __builtin_amdgcn_mfma_f32_16x16x32_bf16(a1, bfrag, acc1, 0, 0, 0);
        acc2 = __builtin_amdgcn_mfma_f32_16x16x32_bf16(a2, bfrag, acc2, 0, 0, 0);
        acc3 = __builtin_amdgcn_mfma_f32_16x16x32_bf16(a3, bfrag, acc3, 0, 0, 0);
        __syncthreads();
    }
    // epilogue: C/D layout col=lane&15, row=(lane>>4)*4+reg
    int cn = n0 + wave * 16 + r16;
    float bv = bias ? bias[cn] : 0.f;
    floatx4 aa[4] = {acc0, acc1, acc2, acc3};
    for (int ms = 0; ms < 4; ++ms)
        for (int rr = 0; rr < 4; ++rr) {
            int cm = m0 + ms * 16 + q * 4 + rr;
            if (cm < M) {
                float v = aa[ms][rr] + bv;
                if (act) v = lrelu(v, slope);
                if (oscale) v *= oscale[cm];
                C[(size_t)cm * Nc + cn] = f2bf(v);
            }
        }
}

// ---------------- GAT ----------------

__global__ __launch_bounds__(256) void gat_dots(const unsigned short* __restrict__ hg, const float* __restrict__ att_s,
                                                const float* __restrict__ att_d,
                                                float* __restrict__ a_s, float* __restrict__ a_d, int n) {
    int node = blockIdx.x * 4 + (threadIdx.x >> 6);
    if (node >= n) return;
    int lane = threadIdx.x & 63;
    float v  = bf2f(hg[(size_t)node * 64 + lane]);
    float s1 = v * att_s[lane];
    float s2 = v * att_d[lane];
    for (int off = 32; off > 0; off >>= 1) {
        s1 += __shfl_xor(s1, off, 64);
        s2 += __shfl_xor(s2, off, 64);
    }
    if (lane == 0) { a_s[node] = s1; a_d[node] = s2; }
}

// 8 edges in flight: 8 slots x 8 lanes, uint4 (8 feats) per lane (row = 64 bf16 = 8 uint4).
// No segment-max pass: e = lrelu(a_s+a_d) is O(1..10) << 88, exp(e) fp32-safe; shift cancels.
__global__ __launch_bounds__(256) void gat_agg(const uint4* __restrict__ hg, const float* __restrict__ a_s,
                                               const float* __restrict__ a_d, const int* __restrict__ offs,
                                               const int* __restrict__ csr_s, const float* __restrict__ bg,
                                               uint4* __restrict__ out, int n) {
    int node = blockIdx.x * 4 + (threadIdx.x >> 6);
    if (node >= n) return;
    int lane = threadIdx.x & 63;
    int slot = lane >> 3;      // 0..7
    int li   = lane & 7;       // uint4 index within row
    int beg = offs[node], end = offs[node + 1];
    float ad = a_d[node];
    float a0=0.f,a1=0.f,a2=0.f,a3=0.f,a4=0.f,a5=0.f,a6=0.f,a7=0.f, ssum=0.f;
    for (int base = beg; base < end; base += 64) {
        int cnt = end - base; if (cnt > 64) cnt = 64;
        int sj = 0; float wj = 0.f;
        if (lane < cnt) {
            sj = csr_s[base + lane];
            float e = a_s[sj] + ad;
            e = e < 0.f ? 0.2f * e : e;
            wj = __expf(e);
        }
        for (int t = 0; t < cnt; t += 8) {
            int idx  = t + slot;
            int idxc = idx < cnt ? idx : 0;
            int   s = __shfl(sj, idxc, 64);
            float w = __shfl(wj, idxc, 64);
            if (idx >= cnt) w = 0.f;
            ssum += w;
            uint4 u = hg[(size_t)s * 8 + li];
            a0 = fmaf(w, bflo(u.x), a0); a1 = fmaf(w, bfhi(u.x), a1);
            a2 = fmaf(w, bflo(u.y), a2); a3 = fmaf(w, bfhi(u.y), a3);
            a4 = fmaf(w, bflo(u.z), a4); a5 = fmaf(w, bfhi(u.z), a5);
            a6 = fmaf(w, bflo(u.w), a6); a7 = fmaf(w, bfhi(u.w), a7);
        }
    }
    for (int off = 8; off <= 32; off <<= 1) {
        a0 += __shfl_xor(a0, off, 64); a1 += __shfl_xor(a1, off, 64);
        a2 += __shfl_xor(a2, off, 64); a3 += __shfl_xor(a3, off, 64);
        a4 += __shfl_xor(a4, off, 64); a5 += __shfl_xor(a5, off, 64);
        a6 += __shfl_xor(a6, off, 64); a7 += __shfl_xor(a7, off, 64);
        ssum += __shfl_xor(ssum, off, 64);
    }
    if (slot == 0) {
        float inv = 1.0f / ssum;
        int f0 = li * 8;
        uint4 o;
        o.x = pack2bf(lrelu(a0 * inv + bg[f0 + 0], 0.1f), lrelu(a1 * inv + bg[f0 + 1], 0.1f));
        o.y = pack2bf(lrelu(a2 * inv + bg[f0 + 2], 0.1f), lrelu(a3 * inv + bg[f0 + 3], 0.1f));
        o.z = pack2bf(lrelu(a4 * inv + bg[f0 + 4], 0.1f), lrelu(a5 * inv + bg[f0 + 5], 0.1f));
        o.w = pack2bf(lrelu(a6 * inv + bg[f0 + 6], 0.1f), lrelu(a7 * inv + bg[f0 + 7], 0.1f));
        out[(size_t)node * 8 + li] = o;
    }
}

// ---------------- final small GEMM [Ng,256]@[256,8] + bias -> fp32 ----------------

__global__ __launch_bounds__(256) void final_gemm(const unsigned short* __restrict__ m2, const float* __restrict__ W3,
                                                  const float* __restrict__ b3,
                                                  float* __restrict__ out, int ng) {
    int idx = blockIdx.x * 256 + threadIdx.x;
    if (idx >= ng * 8) return;
    int r = idx >> 3, c = idx & 7;
    float acc = b3[c];
    const unsigned short* row = m2 + (size_t)r * 256;
    for (int k = 0; k < 256; ++k) acc = fmaf(bf2f(row[k]), W3[k * 8 + c], acc);
    out[idx] = acc;
}

// ---------------- launch ----------------

extern "C" void kernel_launch(void* const* d_in, const int* in_sizes, int n_in,
                              void* d_out, int out_size, void* d_ws, size_t ws_size,
                              hipStream_t stream) {
    const int N  = in_sizes[0] / 128;
    const int E  = in_sizes[1] / 2;
    const int ET = E + N;
    const int Ng = N / 10;
    const int NB = (N + 127) / 128;   // dst buckets (<= NBQ)

    const float* x    = (const float*)d_in[0];
    const int*   src  = (const int*)d_in[1];
    const int*   dst  = src + E;
    const float* W1   = (const float*)d_in[2];
    const float* b1   = (const float*)d_in[3];
    const float* W2   = (const float*)d_in[4];
    const float* b2   = (const float*)d_in[5];
    const float* Wg   = (const float*)d_in[6];
    const float* atts = (const float*)d_in[7];
    const float* attd = (const float*)d_in[8];
    const float* bg   = (const float*)d_in[9];
    const float* Wl1  = (const float*)d_in[10];
    const float* bl1  = (const float*)d_in[11];
    const float* Wl2  = (const float*)d_in[12];
    const float* bl2  = (const float*)d_in[13];
    const float* Wl3  = (const float*)d_in[14];
    const float* bl3  = (const float*)d_in[15];
    float* out = (float*)d_out;

    // bf16 weight buffer segment sizes (pairs)
    const int p1 = in_sizes[2] / 2;    // W1
    const int p2 = in_sizes[4] / 2;    // W2
    const int p3 = in_sizes[6] / 2;    // Wg
    const int p4 = in_sizes[10] / 2;   // Wl1
    const int p5 = in_sizes[12] / 2;   // Wl2
    const int c0 = p1, c1 = c0 + p2, c2 = c1 + p3, c3 = c2 + p4, c4 = c3 + p5;

    // workspace carve (all feature buffers bf16, 16B-aligned rows)
    char* p = (char*)d_ws;
    auto alloc = [&](size_t bytes) { char* r = p; p += (bytes + 255) & ~(size_t)255; return r; };
    unsigned short* xb = (unsigned short*)alloc((size_t)N * 128 * 2);
    unsigned short* A  = (unsigned short*)alloc((size_t)N * 128 * 2);
    unsigned short* Bb = (unsigned short*)alloc((size_t)N * 128 * 2);
    int*   csr_s   = (int*)  alloc((size_t)ET * 4);
    int*   cnt     = (int*)  alloc((size_t)NBLK * NBQ * 4);
    int*   btot    = (int*)  alloc((size_t)(NBQ + 1) * 4);
    int*   bbase   = (int*)  alloc((size_t)(NBQ + 1) * 4);
    float* dinv    = (float*)alloc((size_t)N * 4);
    int*   offsets = (int*)  alloc((size_t)(N + 1) * 4);
    float* a_s     = (float*)alloc((size_t)N * 4);
    float* a_d     = (float*)alloc((size_t)N * 4);
    unsigned short* wb = (unsigned short*)alloc((size_t)c4 * 4);  // packed bf16 weights
    // ebuf ({src,dst} pairs, ET*8 bytes) aliases Bb (N*128*2 = 25.6MB > 13.6MB);
    // its lifetime ends before Bb's first write.
    int2*  ebuf    = (int2*)Bb;

    const unsigned short* W1b  = wb;
    const unsigned short* W2b  = wb + 2 * (size_t)c0;
    const unsigned short* Wgb  = wb + 2 * (size_t)c1;
    const unsigned short* Wl1b = wb + 2 * (size_t)c2;
    const unsigned short* Wl2b = wb + 2 * (size_t)c3;

    const int pg = (N + 3) / 4;

    hist_k    <<<NBLK, 256, 0, stream>>>(dst, cnt, E, ET, NB);
    btot_k    <<<(NB + 255) / 256, 256, 0, stream>>>(cnt, btot, NB);
    bscan_k   <<<1, 256, 0, stream>>>(btot, bbase, NB, ET);
    scan_cnt  <<<(NB + 255) / 256, 256, 0, stream>>>(cnt, bbase, NB);
    scatter_k <<<NBLK, 256, 0, stream>>>(src, dst, cnt, ebuf, E, ET, NB);
    finalize_k<<<NB, 256, 0, stream>>>(ebuf, bbase, offsets, dinv, csr_s, N, ET);
    wcast     <<<(c4 + 255) / 256, 256, 0, stream>>>(W1, W2, Wg, Wl1, Wl2, (unsigned*)wb, c0, c1, c2, c3, c4);
    cast_scale<<<(N * 64 + 255) / 256, 256, 0, stream>>>(x, dinv, (unsigned*)xb, N * 64);

    // conv1: u = D^-1/2 x (cast) ; A = D^-1 A u ; Bb = D^-1/2 A A' = P^2 x ; h1' = lrelu(...)*dinv
    prop_kernel<<<pg, 256, 0, stream>>>((const uint4*)xb, offsets, csr_s, dinv, 1, (uint4*)A,  N);
    prop_kernel<<<pg, 256, 0, stream>>>((const uint4*)A,  offsets, csr_s, dinv, 0, (uint4*)Bb, N);
    dim3 g1((N + 63) / 64, 2);
    gemm_mfma<<<g1, 256, 0, stream>>>(Bb, W1b, b1, A, dinv, N, 128, 128, 0.1f, 1);
    // conv2 (input already dinv-prescaled by gemm1 epilogue)
    prop_kernel<<<pg, 256, 0, stream>>>((const uint4*)A,  offsets, csr_s, dinv, 1, (uint4*)Bb, N);
    prop_kernel<<<pg, 256, 0, stream>>>((const uint4*)Bb, offsets, csr_s, dinv, 0, (uint4*)A,  N);
    gemm_mfma<<<g1, 256, 0, stream>>>(A, W2b, b2, Bb, nullptr, N, 128, 128, 0.1f, 1);
    // GAT: hg = h2 @ Wg (no bias/act), then attention aggregate
    dim3 g2((N + 63) / 64, 1);
    gemm_mfma<<<g2, 256, 0, stream>>>(Bb, Wgb, nullptr, A, nullptr, N, 128, 64, 0.f, 0);
    gat_dots<<<pg, 256, 0, stream>>>(A, atts, attd, a_s, a_d, N);
    gat_agg <<<pg, 256, 0, stream>>>((const uint4*)A, a_s, a_d, offsets, csr_s, bg, (uint4*)Bb, N);
    // MLP: Bb viewed as [Ng, 640] bf16
    dim3 g3((Ng + 63) / 64, 8);
    gemm_mfma<<<g3, 256, 0, stream>>>(Bb, Wl1b, bl1, A, nullptr, Ng, 640, 512, 0.1f, 1);
    dim3 g4((Ng + 63) / 64, 4);
    gemm_mfma<<<g4, 256, 0, stream>>>(A, Wl2b, bl2, Bb, nullptr, Ng, 512, 256, 0.1f, 1);
    final_gemm<<<(Ng * 8 + 255) / 256, 256, 0, stream>>>(Bb, Wl3, bl3, out, Ng);
}

// Round 15
// 647.715 us; speedup vs baseline: 1.0869x; 1.0067x over previous
//
#include <hip/hip_runtime.h>

typedef __attribute__((ext_vector_type(8))) short short8;
typedef __attribute__((ext_vector_type(8))) unsigned short ushort8;
typedef __attribute__((ext_vector_type(4))) float floatx4;

#define NBQ  1024     // max buckets (N <= 131072 @ 128 nodes/bucket; packing needs N <= 2^17)
#define NBLK 128      // sort blocks

__device__ __forceinline__ float bf2f(unsigned short u) {
    union { unsigned u; float f; } v; v.u = ((unsigned)u) << 16; return v.f;
}
__device__ __forceinline__ float bflo(unsigned u) {
    union { unsigned u; float f; } v; v.u = u << 16; return v.f;
}
__device__ __forceinline__ float bfhi(unsigned u) {
    union { unsigned u; float f; } v; v.u = u & 0xFFFF0000u; return v.f;
}
__device__ __forceinline__ unsigned short f2bf(float f) {
    union { float f; unsigned u; } v; v.f = f;
    unsigned r = v.u + 0x7FFFu + ((v.u >> 16) & 1u);
    return (unsigned short)(r >> 16);
}
__device__ __forceinline__ unsigned pack2bf(float a, float b) {
    return (unsigned)f2bf(a) | ((unsigned)f2bf(b) << 16);
}
__device__ __forceinline__ float lrelu(float x, float s) { return x >= 0.f ? x : s * x; }

// fp32 -> bf16 pairs, pre-scaled by dinv[node] (D^-1/2 absorbed into features)
__global__ __launch_bounds__(256) void cast_scale(const float* __restrict__ in, const float* __restrict__ dinv,
                                                  unsigned* __restrict__ outp, int npairs) {
    int i = blockIdx.x * 256 + threadIdx.x;
    if (i < npairs) {
        float s = dinv[i >> 6];
        float2 v = *(const float2*)(in + 2 * (size_t)i);
        outp[i] = pack2bf(v.x * s, v.y * s);
    }
}

// one-shot fp32 -> bf16 cast of 5 weight matrices into one packed buffer
__global__ __launch_bounds__(256) void wcast(const float* __restrict__ w0, const float* __restrict__ w1,
                                             const float* __restrict__ w2, const float* __restrict__ w3,
                                             const float* __restrict__ w4, unsigned* __restrict__ outp,
                                             int c0, int c1, int c2, int c3, int c4) {
    int i = blockIdx.x * 256 + threadIdx.x;
    if (i >= c4) return;
    const float* src; int base;
    if      (i < c0) { src = w0; base = 0;  }
    else if (i < c1) { src = w1; base = c0; }
    else if (i < c2) { src = w2; base = c1; }
    else if (i < c3) { src = w3; base = c2; }
    else             { src = w4; base = c3; }
    float2 v = *(const float2*)(src + 2 * (size_t)(i - base));
    outp[i] = pack2bf(v.x, v.y);
}

// ---- CSR build: two-phase counting sort (bucket = 128 dst nodes), no global atomics ----
__global__ __launch_bounds__(256) void hist_k(const int* __restrict__ dst, int* __restrict__ cnt,
                                              int e, int et, int nb) {
    __shared__ int h[NBQ];
    for (int i = threadIdx.x; i < nb; i += 256) h[i] = 0;
    __syncthreads();
    int chunk = (et + NBLK - 1) / NBLK;
    int c0 = blockIdx.x * chunk;
    int c1 = c0 + chunk < et ? c0 + chunk : et;
    for (int i = c0 + (int)threadIdx.x; i < c1; i += 256) {
        int d = (i < e) ? dst[i] : (i - e);
        atomicAdd(&h[d >> 7], 1);
    }
    __syncthreads();
    for (int i = threadIdx.x; i < nb; i += 256) cnt[blockIdx.x * NBQ + i] = h[i];
}

__global__ __launch_bounds__(256) void btot_k(const int* __restrict__ cnt, int* __restrict__ btot, int nb) {
    int b = blockIdx.x * 256 + threadIdx.x;
    if (b >= nb) return;
    int s = 0;
    for (int blk = 0; blk < NBLK; ++blk) s += cnt[blk * NBQ + b];
    btot[b] = s;
}

__global__ __launch_bounds__(256) void bscan_k(const int* __restrict__ btot, int* __restrict__ bbase,
                                               int nb, int et) {
    __shared__ int sd[256];
    int t = threadIdx.x;
    int i0 = t * 4;
    int loc[4]; int s = 0;
    for (int j = 0; j < 4; ++j) { int i = i0 + j; loc[j] = (i < nb) ? btot[i] : 0; s += loc[j]; }
    sd[t] = s; __syncthreads();
    for (int off = 1; off < 256; off <<= 1) {
        int v = (t >= off) ? sd[t - off] : 0;
        __syncthreads();
        sd[t] += v;
        __syncthreads();
    }
    int run = sd[t] - s;
    for (int j = 0; j < 4; ++j) {
        int i = i0 + j;
        if (i < nb) { bbase[i] = run; run += loc[j]; }
    }
    if (t == 255) bbase[nb] = et;
}

__global__ __launch_bounds__(256) void scan_cnt(int* __restrict__ cnt, const int* __restrict__ bbase,
                                                int nb) {
    int b = blockIdx.x * 256 + threadIdx.x;
    if (b >= nb) return;
    int base = bbase[b];
    for (int blk = 0; blk < NBLK; ++blk) {
        int* p = &cnt[blk * NBQ + b];
        int t = *p; *p = base; base += t;
    }
}

// scatter packed entries: s (17 bits, N <= 131072) | (d&127) << 17 — 4B/edge
__global__ __launch_bounds__(256) void scatter_k(const int* __restrict__ src, const int* __restrict__ dst,
                                                 const int* __restrict__ cnt,
                                                 int* __restrict__ ebuf, int e, int et, int nb) {
    __shared__ int cur[NBQ];
    for (int i = threadIdx.x; i < nb; i += 256) cur[i] = cnt[blockIdx.x * NBQ + i];
    __syncthreads();
    int chunk = (et + NBLK - 1) / NBLK;
    int c0 = blockIdx.x * chunk;
    int c1 = c0 + chunk < et ? c0 + chunk : et;
    for (int i = c0 + (int)threadIdx.x; i < c1; i += 256) {
        int s, d;
        if (i < e) { s = src[i]; d = dst[i]; }
        else       { s = d = i - e; }            // self loop
        int pos = atomicAdd(&cur[d >> 7], 1);
        ebuf[pos] = s | ((d & 127) << 17);
    }
}

// fused: per-bucket degree count + scan -> offsets/dinv, then node-granular CSR
// placement with LDS cursors (ebuf segment stays L2-hot between the two passes)
__global__ __launch_bounds__(256) void finalize_k(const int* __restrict__ ebuf, const int* __restrict__ bbase,
                                                  int* __restrict__ offsets, float* __restrict__ dinv,
                                                  int* __restrict__ csr_s, int n, int et) {
    __shared__ int ldeg[128];
    __shared__ int lscan[128];
    __shared__ int cur[128];
    int b = blockIdx.x;
    int n0 = b << 7;
    if (threadIdx.x < 128) ldeg[threadIdx.x] = 0;
    __syncthreads();
    int e0 = bbase[b], e1 = bbase[b + 1];
    for (int i = e0 + (int)threadIdx.x; i < e1; i += 256)
        atomicAdd(&ldeg[(ebuf[i] >> 17) & 127], 1);
    __syncthreads();
    if (threadIdx.x < 128) lscan[threadIdx.x] = ldeg[threadIdx.x];
    __syncthreads();
    for (int off = 1; off < 128; off <<= 1) {
        int v = 0;
        if (threadIdx.x < 128 && (int)threadIdx.x >= off) v = lscan[threadIdx.x - off];
        __syncthreads();
        if (threadIdx.x < 128) lscan[threadIdx.x] += v;
        __syncthreads();
    }
    if (threadIdx.x < 128) {
        int base = e0 + lscan[threadIdx.x] - ldeg[threadIdx.x];   // exclusive
        cur[threadIdx.x] = base;
        int node = n0 + threadIdx.x;
        if (node < n) {
            offsets[node] = base;
            dinv[node] = rsqrtf((float)ldeg[threadIdx.x]);         // deg >= 1 (self loop)
        }
    }
    if (b == 0 && threadIdx.x == 0) offsets[n] = et;
    __syncthreads();
    for (int i = e0 + (int)threadIdx.x; i < e1; i += 256) {
        int ent = ebuf[i];
        int pos = atomicAdd(&cur[(ent >> 17) & 127], 1);
        csr_s[pos] = ent & 0x1FFFF;
    }
}

// ---------------- propagation: out[d] = scale(d) * sum_{s in N(d)} x[s], 128 bf16 feats ----------------
// Unweighted neighbor sum (P = D^-1/2 A D^-1/2 decomposed); 4 slots x 16 lanes, uint4/lane.
// sq: scale = dinv^2 (first hop, absorbs D^-1); else scale = dinv (second hop, D^-1/2).

__global__ __launch_bounds__(256) void prop_kernel(const uint4* __restrict__ xin, const int* __restrict__ offs,
                                                   const int* __restrict__ csr_s, const float* __restrict__ dinv,
                                                   int sq, uint4* __restrict__ out, int n) {
    int node = blockIdx.x * 4 + (threadIdx.x >> 6);
    if (node >= n) return;
    int lane = threadIdx.x & 63;
    int slot = lane >> 4;      // 0..3
    int li   = lane & 15;      // uint4 index within 16-uint4 row
    int beg = offs[node], end = offs[node + 1];
    float a0=0.f,a1=0.f,a2=0.f,a3=0.f,a4=0.f,a5=0.f,a6=0.f,a7=0.f;
    for (int base = beg; base < end; base += 64) {
        int cnt = end - base; if (cnt > 64) cnt = 64;
        int sj = (lane < cnt) ? csr_s[base + lane] : 0;
        for (int t = 0; t < cnt; t += 4) {
            int idx  = t + slot;
            int s = __shfl(sj, idx < cnt ? idx : 0, 64);
            if (idx < cnt) {
                uint4 u = xin[(size_t)s * 16 + li];
                a0 += bflo(u.x); a1 += bfhi(u.x);
                a2 += bflo(u.y); a3 += bfhi(u.y);
                a4 += bflo(u.z); a5 += bfhi(u.z);
                a6 += bflo(u.w); a7 += bfhi(u.w);
            }
        }
    }
    // combine the 4 slot partials (lanes differing in bits 4,5 hold same features)
    a0 += __shfl_xor(a0, 16, 64); a0 += __shfl_xor(a0, 32, 64);
    a1 += __shfl_xor(a1, 16, 64); a1 += __shfl_xor(a1, 32, 64);
    a2 += __shfl_xor(a2, 16, 64); a2 += __shfl_xor(a2, 32, 64);
    a3 += __shfl_xor(a3, 16, 64); a3 += __shfl_xor(a3, 32, 64);
    a4 += __shfl_xor(a4, 16, 64); a4 += __shfl_xor(a4, 32, 64);
    a5 += __shfl_xor(a5, 16, 64); a5 += __shfl_xor(a5, 32, 64);
    a6 += __shfl_xor(a6, 16, 64); a6 += __shfl_xor(a6, 32, 64);
    a7 += __shfl_xor(a7, 16, 64); a7 += __shfl_xor(a7, 32, 64);
    if (slot == 0) {
        float f = dinv[node];
        if (sq) f *= f;
        uint4 o;
        o.x = pack2bf(a0 * f, a1 * f); o.y = pack2bf(a2 * f, a3 * f);
        o.z = pack2bf(a4 * f, a5 * f); o.w = pack2bf(a6 * f, a7 * f);
        out[(size_t)node * 16 + li] = o;
    }
}

// ---------------- MFMA GEMM: C[M,Nc] = act(A[M,K] @ B[K,Nc] + bias) [* oscale] ----------------
// Proven 64x64 tile, blockIdx.y = 64-col B tile. A bf16, B bf16 (pre-cast weights),
// bias fp32, C bf16. K%32==0, Nc%64==0.
// Optional fused per-row dots (attS/attD non-null, requires Nc==64, gridDim.y==1, act=0):
// oas[m] = sum_n C[m][n]*attS[n], oad likewise — replaces the separate gat_dots pass.

__global__ __launch_bounds__(256) void gemm_mfma(const unsigned short* __restrict__ A,
                                                 const unsigned short* __restrict__ Bw,
                                                 const float* __restrict__ bias, unsigned short* __restrict__ C,
                                                 const float* __restrict__ oscale,
                                                 const float* __restrict__ attS, const float* __restrict__ attD,
                                                 float* __restrict__ oas, float* __restrict__ oad,
                                                 int M, int K, int Nc, float slope, int act) {
    __shared__ __align__(16) unsigned short As[64 * 40];
    __shared__ __align__(16) unsigned short Bs[64 * 40];
    const int tid  = threadIdx.x;
    const int wave = tid >> 6;
    const int lane = tid & 63;
    const int q    = lane >> 4;
    const int r16  = lane & 15;
    const int m0 = blockIdx.x * 64;
    const int n0 = blockIdx.y * 64;

    floatx4 acc0 = {0.f,0.f,0.f,0.f}, acc1 = acc0, acc2 = acc0, acc3 = acc0;

    const int am = tid >> 2;         // 0..63 (tile row)
    const int ak = (tid & 3) * 8;    // 0..24
    const int bk = tid >> 3;         // 0..31 (k within step)
    const int bn = (tid & 7) * 8;    // 0..56

    for (int k0 = 0; k0 < K; k0 += 32) {
        // stage A tile [64][32] bf16 (straight 16B copy), row stride 40
        {
            int gm = m0 + am;
            ushort8 sv;
            if (gm < M) {
                sv = *(const ushort8*)(A + (size_t)gm * K + k0 + ak);
            } else {
                for (int j = 0; j < 8; ++j) sv[j] = 0;
            }
            *(ushort8*)(&As[am * 40 + ak]) = sv;
        }
        // stage B tile [32][64] transposed -> Bs[n][k] (bf16 source, straight copy)
        {
            ushort8 bv = *(const ushort8*)(Bw + (size_t)(k0 + bk) * Nc + n0 + bn);
            for (int j = 0; j < 8; ++j) Bs[(bn + j) * 40 + bk] = bv[j];
        }
        __syncthreads();
        short8 bfrag = *(const short8*)(&Bs[(wave * 16 + r16) * 40 + q * 8]);
        short8 a0 = *(const short8*)(&As[(r16) * 40 + q * 8]);
        short8 a1 = *(const short8*)(&As[(16 + r16) * 40 + q * 8]);
        short8 a2 = *(const short8*)(&As[(32 + r16) * 40 + q * 8]);
        short8 a3 = *(const short8*)(&As[(48 + r16) * 40 + q * 8]);
        acc0 = __builtin_amdgcn_mfma_f32_16x16x32_bf16(a0, bfrag, acc0, 0, 0, 0);
        acc1 = __builtin_amdgcn_mfma_f32_16x16x32_bf16(a1, bfrag, acc1, 0, 0, 0);
        acc2 = __builtin_amdgcn_mfma_f32_16x16x32_bf16(a2, bfrag, acc2, 0, 0, 0);
        acc3 = __builtin_amdgcn_mfma_f32_16x16x32_bf16(a3, bfrag, acc3, 0, 0, 0);
        __syncthreads();
    }
    // epilogue: C/D layout col=lane&15, row=(lane>>4)*4+reg
    int cn = n0 + wave * 16 + r16;
    float bv = bias ? bias[cn] : 0.f;
    floatx4 aa[4] = {acc0, acc1, acc2, acc3};
    float ps[16], pd[16];
    float avs = attS ? attS[cn] : 0.f;
    float avd = attS ? attD[cn] : 0.f;
    for (int ms = 0; ms < 4; ++ms)
        for (int rr = 0; rr < 4; ++rr) {
            int cm = m0 + ms * 16 + q * 4 + rr;
            float v = aa[ms][rr] + bv;
            if (act) v = lrelu(v, slope);
            if (oscale && cm < M) v *= oscale[cm];
            if (cm < M) C[(size_t)cm * Nc + cn] = f2bf(v);
            ps[ms * 4 + rr] = v * avs;
            pd[ms * 4 + rr] = v * avd;
        }
    if (attS) {
        // reduce over the 16 cols held by this wave's q-group (lanes aligned 16)
        for (int off = 1; off < 16; off <<= 1)
#pragma unroll
            for (int i = 0; i < 16; ++i) {
                ps[i] += __shfl_xor(ps[i], off, 64);
                pd[i] += __shfl_xor(pd[i], off, 64);
            }
        // cross-wave combine in LDS (reuse As; all LDS reads done before last barrier)
        float* sd = (float*)As;
        if (tid < 128) sd[tid] = 0.f;
        __syncthreads();
        if (r16 == 0) {
#pragma unroll
            for (int i = 0; i < 16; ++i) {
                int row = (i >> 2) * 16 + q * 4 + (i & 3);
                atomicAdd(&sd[row], ps[i]);
                atomicAdd(&sd[64 + row], pd[i]);
            }
        }
        __syncthreads();
        if (tid < 64 && m0 + tid < M) {
            oas[m0 + tid] = sd[tid];
            oad[m0 + tid] = sd[64 + tid];
        }
    }
}

// ---------------- GAT ----------------
// 8 edges in flight: 8 slots x 8 lanes, uint4 (8 feats) per lane (row = 64 bf16 = 8 uint4).
// No segment-max pass: e = lrelu(a_s+a_d) is O(1..10) << 88, exp(e) fp32-safe; shift cancels.
__global__ __launch_bounds__(256) void gat_agg(const uint4* __restrict__ hg, const float* __restrict__ a_s,
                                               const float* __restrict__ a_d, const int* __restrict__ offs,
                                               const int* __restrict__ csr_s, const float* __restrict__ bg,
                                               uint4* __restrict__ out, int n) {
    int node = blockIdx.x * 4 + (threadIdx.x >> 6);
    if (node >= n) return;
    int lane = threadIdx.x & 63;
    int slot = lane >> 3;      // 0..7
    int li   = lane & 7;       // uint4 index within row
    int beg = offs[node], end = offs[node + 1];
    float ad = a_d[node];
    float a0=0.f,a1=0.f,a2=0.f,a3=0.f,a4=0.f,a5=0.f,a6=0.f,a7=0.f, ssum=0.f;
    for (int base = beg; base < end; base += 64) {
        int cnt = end - base; if (cnt > 64) cnt = 64;
        int sj = 0; float wj = 0.f;
        if (lane < cnt) {
            sj = csr_s[base + lane];
            float e = a_s[sj] + ad;
            e = e < 0.f ? 0.2f * e : e;
            wj = __expf(e);
        }
        for (int t = 0; t < cnt; t += 8) {
            int idx  = t + slot;
            int idxc = idx < cnt ? idx : 0;
            int   s = __shfl(sj, idxc, 64);
            float w = __shfl(wj, idxc, 64);
            if (idx >= cnt) w = 0.f;
            ssum += w;
            uint4 u = hg[(size_t)s * 8 + li];
            a0 = fmaf(w, bflo(u.x), a0); a1 = fmaf(w, bfhi(u.x), a1);
            a2 = fmaf(w, bflo(u.y), a2); a3 = fmaf(w, bfhi(u.y), a3);
            a4 = fmaf(w, bflo(u.z), a4); a5 = fmaf(w, bfhi(u.z), a5);
            a6 = fmaf(w, bflo(u.w), a6); a7 = fmaf(w, bfhi(u.w), a7);
        }
    }
    for (int off = 8; off <= 32; off <<= 1) {
        a0 += __shfl_xor(a0, off, 64); a1 += __shfl_xor(a1, off, 64);
        a2 += __shfl_xor(a2, off, 64); a3 += __shfl_xor(a3, off, 64);
        a4 += __shfl_xor(a4, off, 64); a5 += __shfl_xor(a5, off, 64);
        a6 += __shfl_xor(a6, off, 64); a7 += __shfl_xor(a7, off, 64);
        ssum += __shfl_xor(ssum, off, 64);
    }
    if (slot == 0) {
        float inv = 1.0f / ssum;
        int f0 = li * 8;
        uint4 o;
        o.x = pack2bf(lrelu(a0 * inv + bg[f0 + 0], 0.1f), lrelu(a1 * inv + bg[f0 + 1], 0.1f));
        o.y = pack2bf(lrelu(a2 * inv + bg[f0 + 2], 0.1f), lrelu(a3 * inv + bg[f0 + 3], 0.1f));
        o.z = pack2bf(lrelu(a4 * inv + bg[f0 + 4], 0.1f), lrelu(a5 * inv + bg[f0 + 5], 0.1f));
        o.w = pack2bf(lrelu(a6 * inv + bg[f0 + 6], 0.1f), lrelu(a7 * inv + bg[f0 + 7], 0.1f));
        out[(size_t)node * 8 + li] = o;
    }
}

// ---------------- final small GEMM [Ng,256]@[256,8] + bias -> fp32 ----------------

__global__ __launch_bounds__(256) void final_gemm(const unsigned short* __restrict__ m2, const float* __restrict__ W3,
                                                  const float* __restrict__ b3,
                                                  float* __restrict__ out, int ng) {
    int idx = blockIdx.x * 256 + threadIdx.x;
    if (idx >= ng * 8) return;
    int r = idx >> 3, c = idx & 7;
    float acc = b3[c];
    const unsigned short* row = m2 + (size_t)r * 256;
    for (int k = 0; k < 256; ++k) acc = fmaf(bf2f(row[k]), W3[k * 8 + c], acc);
    out[idx] = acc;
}

// ---------------- launch ----------------

extern "C" void kernel_launch(void* const* d_in, const int* in_sizes, int n_in,
                              void* d_out, int out_size, void* d_ws, size_t ws_size,
                              hipStream_t stream) {
    const int N  = in_sizes[0] / 128;
    const int E  = in_sizes[1] / 2;
    const int ET = E + N;
    const int Ng = N / 10;
    const int NB = (N + 127) / 128;   // dst buckets (<= NBQ)

    const float* x    = (const float*)d_in[0];
    const int*   src  = (const int*)d_in[1];
    const int*   dst  = src + E;
    const float* W1   = (const float*)d_in[2];
    const float* b1   = (const float*)d_in[3];
    const float* W2   = (const float*)d_in[4];
    const float* b2   = (const float*)d_in[5];
    const float* Wg   = (const float*)d_in[6];
    const float* atts = (const float*)d_in[7];
    const float* attd = (const float*)d_in[8];
    const float* bg   = (const float*)d_in[9];
    const float* Wl1  = (const float*)d_in[10];
    const float* bl1  = (const float*)d_in[11];
    const float* Wl2  = (const float*)d_in[12];
    const float* bl2  = (const float*)d_in[13];
    const float* Wl3  = (const float*)d_in[14];
    const float* bl3  = (const float*)d_in[15];
    float* out = (float*)d_out;

    // bf16 weight buffer segment sizes (pairs)
    const int p1 = in_sizes[2] / 2;    // W1
    const int p2 = in_sizes[4] / 2;    // W2
    const int p3 = in_sizes[6] / 2;    // Wg
    const int p4 = in_sizes[10] / 2;   // Wl1
    const int p5 = in_sizes[12] / 2;   // Wl2
    const int c0 = p1, c1 = c0 + p2, c2 = c1 + p3, c3 = c2 + p4, c4 = c3 + p5;

    // workspace carve (all feature buffers bf16, 16B-aligned rows)
    char* p = (char*)d_ws;
    auto alloc = [&](size_t bytes) { char* r = p; p += (bytes + 255) & ~(size_t)255; return r; };
    unsigned short* xb = (unsigned short*)alloc((size_t)N * 128 * 2);
    unsigned short* A  = (unsigned short*)alloc((size_t)N * 128 * 2);
    unsigned short* Bb = (unsigned short*)alloc((size_t)N * 128 * 2);
    int*   csr_s   = (int*)  alloc((size_t)ET * 4);
    int*   cnt     = (int*)  alloc((size_t)NBLK * NBQ * 4);
    int*   btot    = (int*)  alloc((size_t)(NBQ + 1) * 4);
    int*   bbase   = (int*)  alloc((size_t)(NBQ + 1) * 4);
    float* dinv    = (float*)alloc((size_t)N * 4);
    int*   offsets = (int*)  alloc((size_t)(N + 1) * 4);
    float* a_s     = (float*)alloc((size_t)N * 4);
    float* a_d     = (float*)alloc((size_t)N * 4);
    unsigned short* wb = (unsigned short*)alloc((size_t)c4 * 4);  // packed bf16 weights
    // ebuf (packed src|dlow, ET*4 bytes) aliases Bb; lifetime ends before Bb's first write.
    int*   ebuf    = (int*)Bb;

    const unsigned short* W1b  = wb;
    const unsigned short* W2b  = wb + 2 * (size_t)c0;
    const unsigned short* Wgb  = wb + 2 * (size_t)c1;
    const unsigned short* Wl1b = wb + 2 * (size_t)c2;
    const unsigned short* Wl2b = wb + 2 * (size_t)c3;

    const int pg = (N + 3) / 4;

    hist_k    <<<NBLK, 256, 0, stream>>>(dst, cnt, E, ET, NB);
    btot_k    <<<(NB + 255) / 256, 256, 0, stream>>>(cnt, btot, NB);
    bscan_k   <<<1, 256, 0, stream>>>(btot, bbase, NB, ET);
    scan_cnt  <<<(NB + 255) / 256, 256, 0, stream>>>(cnt, bbase, NB);
    scatter_k <<<NBLK, 256, 0, stream>>>(src, dst, cnt, ebuf, E, ET, NB);
    finalize_k<<<NB, 256, 0, stream>>>(ebuf, bbase, offsets, dinv, csr_s, N, ET);
    wcast     <<<(c4 + 255) / 256, 256, 0, stream>>>(W1, W2, Wg, Wl1, Wl2, (unsigned*)wb, c0, c1, c2, c3, c4);
    cast_scale<<<(N * 64 + 255) / 256, 256, 0, stream>>>(x, dinv, (unsigned*)xb, N * 64);

    // conv1: u = D^-1/2 x (cast) ; A = D^-1 A u ; Bb = D^-1/2 A A' = P^2 x ; h1' = lrelu(...)*dinv
    prop_kernel<<<pg, 256, 0, stream>>>((const uint4*)xb, offsets, csr_s, dinv, 1, (uint4*)A,  N);
    prop_kernel<<<pg, 256, 0, stream>>>((const uint4*)A,  offsets, csr_s, dinv, 0, (uint4*)Bb, N);
    dim3 g1((N + 63) / 64, 2);
    gemm_mfma<<<g1, 256, 0, stream>>>(Bb, W1b, b1, A, dinv, nullptr, nullptr, nullptr, nullptr,
                                      N, 128, 128, 0.1f, 1);
    // conv2 (input already dinv-prescaled by gemm1 epilogue)
    prop_kernel<<<pg, 256, 0, stream>>>((const uint4*)A,  offsets, csr_s, dinv, 1, (uint4*)Bb, N);
    prop_kernel<<<pg, 256, 0, stream>>>((const uint4*)Bb, offsets, csr_s, dinv, 0, (uint4*)A,  N);
    gemm_mfma<<<g1, 256, 0, stream>>>(A, W2b, b2, Bb, nullptr, nullptr, nullptr, nullptr, nullptr,
                                      N, 128, 128, 0.1f, 1);
    // GAT: hg = h2 @ Wg with fused a_s/a_d row-dots, then attention aggregate
    dim3 g2((N + 63) / 64, 1);
    gemm_mfma<<<g2, 256, 0, stream>>>(Bb, Wgb, nullptr, A, nullptr, atts, attd, a_s, a_d,
                                      N, 128, 64, 0.f, 0);
    gat_agg <<<pg, 256, 0, stream>>>((const uint4*)A, a_s, a_d, offsets, csr_s, bg, (uint4*)Bb, N);
    // MLP: Bb viewed as [Ng, 640] bf16
    dim3 g3((Ng + 63) / 64, 8);
    gemm_mfma<<<g3, 256, 0, stream>>>(Bb, Wl1b, bl1, A, nullptr, nullptr, nullptr, nullptr, nullptr,
                                      Ng, 640, 512, 0.1f, 1);
    dim3 g4((Ng + 63) / 64, 4);
    gemm_mfma<<<g4, 256, 0, stream>>>(A, Wl2b, bl2, Bb, nullptr, nullptr, nullptr, nullptr, nullptr,
                                      Ng, 512, 256, 0.1f, 1);
    final_gemm<<<(Ng * 8 + 255) / 256, 256, 0, stream>>>(Bb, Wl3, bl3, out, Ng);
}